// Round 1
// baseline (441.747 us; speedup 1.0000x reference)
//
#include <hip/hip_runtime.h>

#define D 128

// ---------------- CSR build ----------------

__global__ __launch_bounds__(256) void k_count(const int* __restrict__ dst,
                                               int* __restrict__ cnt, int E) {
    int e = blockIdx.x * 256 + threadIdx.x;
    if (e < E) atomicAdd(&cnt[dst[e]], 1);
}

// exclusive scan, chunked: 2048 elems/block
__global__ __launch_bounds__(256) void k_scan_chunk(const int* __restrict__ cnt,
                                                    int* __restrict__ row_ptr,
                                                    int* __restrict__ partial, int N) {
    __shared__ int s[256];
    int t = threadIdx.x;
    int base = blockIdx.x * 2048 + t * 8;
    int v[8];
    int sum = 0;
#pragma unroll
    for (int i = 0; i < 8; ++i) {
        v[i] = sum;
        int idx = base + i;
        sum += (idx < N) ? cnt[idx] : 0;
    }
    s[t] = sum;
    __syncthreads();
    for (int off = 1; off < 256; off <<= 1) {
        int x = (t >= off) ? s[t - off] : 0;
        __syncthreads();
        s[t] += x;
        __syncthreads();
    }
    int exc = s[t] - sum;  // exclusive prefix of this thread's chunk
#pragma unroll
    for (int i = 0; i < 8; ++i) {
        int idx = base + i;
        if (idx < N) row_ptr[idx] = exc + v[i];
    }
    if (t == 255) partial[blockIdx.x] = s[255];
}

__global__ __launch_bounds__(256) void k_scan_add(int* __restrict__ row_ptr,
                                                  const int* __restrict__ partial,
                                                  int N, int nChunks) {
    __shared__ int soff;
    int chunk = blockIdx.x;
    if (threadIdx.x == 0) {
        int o = 0;
        for (int j = 0; j < chunk; ++j) o += partial[j];
        soff = o;
    }
    __syncthreads();
    int off = soff;
    int lo = chunk * 2048;
    int hi = (chunk + 1) * 2048; if (hi > N) hi = N;
    for (int i = lo + threadIdx.x; i < hi; i += 256) row_ptr[i] += off;
    if (chunk == nChunks - 1 && threadIdx.x == 0) row_ptr[N] = off + partial[chunk];
}

__global__ __launch_bounds__(256) void k_fill(const int* __restrict__ src,
                                              const int* __restrict__ dst,
                                              const int* __restrict__ row_ptr,
                                              int* __restrict__ cnt,
                                              int* __restrict__ col, int E) {
    int e = blockIdx.x * 256 + threadIdx.x;
    if (e >= E) return;
    int d = dst[e];
    int p = atomicAdd(&cnt[d], 1);
    col[row_ptr[d] + p] = src[e];
}

// ---------------- mean aggregation, 128-wide: one wave per node ----------------

__global__ __launch_bounds__(256) void k_agg128(const float* __restrict__ h,
                                                const int* __restrict__ row_ptr,
                                                const int* __restrict__ col,
                                                float* __restrict__ hn, int N) {
    int w = (blockIdx.x * 256 + threadIdx.x) >> 6;
    int lane = threadIdx.x & 63;
    if (w >= N) return;
    int beg = row_ptr[w], end = row_ptr[w + 1];
    float ax = 0.f, ay = 0.f;
    for (int j = beg; j < end; ++j) {
        int s = col[j];
        float2 v = *(const float2*)&h[(size_t)s * D + lane * 2];
        ax += v.x;
        ay += v.y;
    }
    float inv = 1.0f / fmaxf((float)(end - beg), 1.0f);
    float2 o;
    o.x = ax * inv;
    o.y = ay * inv;
    *(float2*)&hn[(size_t)w * D + lane * 2] = o;
}

// ---------------- fused SAGE GEMM: out = h@Ws + hn@Wn + b, optional relu ----------------
// block tile: 64 rows x 128 cols; 256 threads = 32 col-threads (x4 cols, float4) x 8 row-threads (x8 rows)
// K folded as two phases (self then neigh) sharing LDS.

__global__ __launch_bounds__(256) void k_gemm(const float* __restrict__ h,
                                              const float* __restrict__ hn,
                                              const float* __restrict__ Ws,
                                              const float* __restrict__ Wn,
                                              const float* __restrict__ b,
                                              float* __restrict__ out, int N, int relu) {
    __shared__ float Wl[D * D];    // 64KB
    __shared__ float Al[64 * D];   // 32KB
    int tid = threadIdx.x;
    int ct = tid & 31;   // col group: cols 4*ct .. 4*ct+3
    int rt = tid >> 5;   // row group: rows rt*8 .. rt*8+7
    int rowBase = blockIdx.x * 64;
    float acc[8][4];
#pragma unroll
    for (int r = 0; r < 8; ++r) {
        acc[r][0] = 0.f; acc[r][1] = 0.f; acc[r][2] = 0.f; acc[r][3] = 0.f;
    }
    for (int ph = 0; ph < 2; ++ph) {
        const float* W = ph ? Wn : Ws;
        const float* A = ph ? hn : h;
        for (int i = tid * 4; i < D * D; i += 1024)
            *(float4*)&Wl[i] = *(const float4*)&W[i];
        for (int i = tid * 4; i < 64 * D; i += 1024) {
            int r = i >> 7, k = i & (D - 1);
            int row = rowBase + r;
            float4 v = {0.f, 0.f, 0.f, 0.f};
            if (row < N) v = *(const float4*)&A[(size_t)row * D + k];
            *(float4*)&Al[i] = v;
        }
        __syncthreads();
#pragma unroll 4
        for (int k = 0; k < D; ++k) {
            float4 wv = *(const float4*)&Wl[k * D + ct * 4];
#pragma unroll
            for (int r = 0; r < 8; ++r) {
                float a = Al[(rt * 8 + r) * D + k];
                acc[r][0] += a * wv.x;
                acc[r][1] += a * wv.y;
                acc[r][2] += a * wv.z;
                acc[r][3] += a * wv.w;
            }
        }
        __syncthreads();
    }
    float4 bb = *(const float4*)&b[ct * 4];
#pragma unroll
    for (int r = 0; r < 8; ++r) {
        int row = rowBase + rt * 8 + r;
        if (row < N) {
            float4 o;
            o.x = acc[r][0] + bb.x;
            o.y = acc[r][1] + bb.y;
            o.z = acc[r][2] + bb.z;
            o.w = acc[r][3] + bb.w;
            if (relu) {
                o.x = fmaxf(o.x, 0.f); o.y = fmaxf(o.y, 0.f);
                o.z = fmaxf(o.z, 0.f); o.w = fmaxf(o.w, 0.f);
            }
            *(float4*)&out[(size_t)row * D + ct * 4] = o;
        }
    }
}

// ---------------- layer 2 (dout=2): self-term + neighbor projection ----------------
// out[n] = h[n]@Ws2 + b2 ; p[n] = h[n]@Wn2   (aggregate p afterwards: mean-agg is linear)

__global__ __launch_bounds__(256) void k_l2(const float* __restrict__ h,
                                            const float* __restrict__ Ws,
                                            const float* __restrict__ Wn,
                                            const float* __restrict__ b,
                                            float* __restrict__ out,
                                            float* __restrict__ p, int N) {
    int w = (blockIdx.x * 256 + threadIdx.x) >> 6;
    int lane = threadIdx.x & 63;
    if (w >= N) return;
    float2 hv = *(const float2*)&h[(size_t)w * D + lane * 2];
    float4 ws = *(const float4*)&Ws[lane * 4];  // rows 2*lane, 2*lane+1 of [128][2]
    float4 wn = *(const float4*)&Wn[lane * 4];
    float s0 = hv.x * ws.x + hv.y * ws.z;
    float s1 = hv.x * ws.y + hv.y * ws.w;
    float q0 = hv.x * wn.x + hv.y * wn.z;
    float q1 = hv.x * wn.y + hv.y * wn.w;
    for (int off = 32; off; off >>= 1) {
        s0 += __shfl_xor(s0, off);
        s1 += __shfl_xor(s1, off);
        q0 += __shfl_xor(q0, off);
        q1 += __shfl_xor(q1, off);
    }
    if (lane == 0) {
        out[w * 2 + 0] = s0 + b[0];
        out[w * 2 + 1] = s1 + b[1];
        p[w * 2 + 0] = q0;
        p[w * 2 + 1] = q1;
    }
}

__global__ __launch_bounds__(256) void k_l2agg(const float* __restrict__ p,
                                               const int* __restrict__ row_ptr,
                                               const int* __restrict__ col,
                                               float* __restrict__ out, int N) {
    int n = blockIdx.x * 256 + threadIdx.x;
    if (n >= N) return;
    int beg = row_ptr[n], end = row_ptr[n + 1];
    float a0 = 0.f, a1 = 0.f;
    for (int j = beg; j < end; ++j) {
        int s = col[j];
        float2 v = *(const float2*)&p[(size_t)s * 2];
        a0 += v.x;
        a1 += v.y;
    }
    float inv = 1.0f / fmaxf((float)(end - beg), 1.0f);
    out[n * 2 + 0] += a0 * inv;
    out[n * 2 + 1] += a1 * inv;
}

// ---------------- launch ----------------

extern "C" void kernel_launch(void* const* d_in, const int* in_sizes, int n_in,
                              void* d_out, int out_size, void* d_ws, size_t ws_size,
                              hipStream_t stream) {
    const float* x   = (const float*)d_in[0];
    const int*   src = (const int*)d_in[1];
    const int*   dst = (const int*)d_in[2];
    const float* Ws0 = (const float*)d_in[3];
    const float* Wn0 = (const float*)d_in[4];
    const float* b0  = (const float*)d_in[5];
    const float* Ws1 = (const float*)d_in[6];
    const float* Wn1 = (const float*)d_in[7];
    const float* b1  = (const float*)d_in[8];
    const float* Ws2 = (const float*)d_in[9];
    const float* Wn2 = (const float*)d_in[10];
    const float* b2  = (const float*)d_in[11];
    float* out = (float*)d_out;

    int N = in_sizes[0] / D;  // 50000
    int E = in_sizes[1];      // 600000

    // workspace carve (~54.4 MB)
    float* bufA = (float*)d_ws;                     // N*D
    float* bufB = bufA + (size_t)N * D;             // N*D
    float* p    = bufB;                             // reuse bufB for [N,2] proj (free at layer 2)
    int* row_ptr = (int*)(bufA + 2 * (size_t)N * D);  // N+1
    int* cnt     = row_ptr + (N + 2);                  // N
    int* partial = cnt + N;                            // <=64
    int* col     = partial + 64;                       // E

    // CSR build (per call; deterministic work)
    hipMemsetAsync(cnt, 0, (size_t)N * sizeof(int), stream);
    k_count<<<(E + 255) / 256, 256, 0, stream>>>(dst, cnt, E);
    int nChunks = (N + 2047) / 2048;
    k_scan_chunk<<<nChunks, 256, 0, stream>>>(cnt, row_ptr, partial, N);
    k_scan_add<<<nChunks, 256, 0, stream>>>(row_ptr, partial, N, nChunks);
    hipMemsetAsync(cnt, 0, (size_t)N * sizeof(int), stream);
    k_fill<<<(E + 255) / 256, 256, 0, stream>>>(src, dst, row_ptr, cnt, col, E);

    int aggGrid  = (N * 64 + 255) / 256;  // one wave per node
    int gemmGrid = (N + 63) / 64;

    // layer 0: h1 = relu(x@Ws0 + mean(x)@Wn0 + b0)   -> bufB (in-place over agg)
    k_agg128<<<aggGrid, 256, 0, stream>>>(x, row_ptr, col, bufB, N);
    k_gemm<<<gemmGrid, 256, 0, stream>>>(x, bufB, Ws0, Wn0, b0, bufB, N, 1);

    // layer 1: h2 = relu(h1@Ws1 + mean(h1)@Wn1 + b1) -> bufA
    k_agg128<<<aggGrid, 256, 0, stream>>>(bufB, row_ptr, col, bufA, N);
    k_gemm<<<gemmGrid, 256, 0, stream>>>(bufB, bufA, Ws1, Wn1, b1, bufA, N, 1);

    // layer 2: out = h2@Ws2 + mean(h2@Wn2) + b2  (project-then-aggregate, 2-wide)
    k_l2<<<aggGrid, 256, 0, stream>>>(bufA, Ws2, Wn2, b2, out, p, N);
    k_l2agg<<<(N + 255) / 256, 256, 0, stream>>>(p, row_ptr, col, out, N);
}

// Round 2
// 289.857 us; speedup vs baseline: 1.5240x; 1.5240x over previous
//
#include <hip/hip_runtime.h>

#define D 128

typedef __attribute__((ext_vector_type(8))) short short8;
typedef __attribute__((ext_vector_type(4))) float f32x4;

// f32 -> bf16 round-to-nearest-even
__device__ inline unsigned short f2b(float f) {
    unsigned u = __float_as_uint(f);
    u += 0x7FFFu + ((u >> 16) & 1u);
    return (unsigned short)(u >> 16);
}
__device__ inline float b2f_lo(unsigned v) { return __uint_as_float(v << 16); }
__device__ inline float b2f_hi(unsigned v) { return __uint_as_float(v & 0xFFFF0000u); }

// ---------------- CSR build ----------------

__global__ __launch_bounds__(256) void k_count(const int* __restrict__ dst,
                                               int* __restrict__ cnt, int E) {
    int e = blockIdx.x * 256 + threadIdx.x;
    if (e < E) atomicAdd(&cnt[dst[e]], 1);
}

__global__ __launch_bounds__(256) void k_scan_chunk(const int* __restrict__ cnt,
                                                    int* __restrict__ row_ptr,
                                                    int* __restrict__ partial, int N) {
    __shared__ int s[256];
    int t = threadIdx.x;
    int base = blockIdx.x * 2048 + t * 8;
    int v[8];
    int sum = 0;
#pragma unroll
    for (int i = 0; i < 8; ++i) {
        v[i] = sum;
        int idx = base + i;
        sum += (idx < N) ? cnt[idx] : 0;
    }
    s[t] = sum;
    __syncthreads();
    for (int off = 1; off < 256; off <<= 1) {
        int x = (t >= off) ? s[t - off] : 0;
        __syncthreads();
        s[t] += x;
        __syncthreads();
    }
    int exc = s[t] - sum;
#pragma unroll
    for (int i = 0; i < 8; ++i) {
        int idx = base + i;
        if (idx < N) row_ptr[idx] = exc + v[i];
    }
    if (t == 255) partial[blockIdx.x] = s[255];
}

__global__ __launch_bounds__(256) void k_scan_add(int* __restrict__ row_ptr,
                                                  const int* __restrict__ partial,
                                                  int N, int nChunks) {
    __shared__ int soff;
    int chunk = blockIdx.x;
    if (threadIdx.x == 0) {
        int o = 0;
        for (int j = 0; j < chunk; ++j) o += partial[j];
        soff = o;
    }
    __syncthreads();
    int off = soff;
    int lo = chunk * 2048;
    int hi = (chunk + 1) * 2048; if (hi > N) hi = N;
    for (int i = lo + threadIdx.x; i < hi; i += 256) row_ptr[i] += off;
    if (chunk == nChunks - 1 && threadIdx.x == 0) row_ptr[N] = off + partial[chunk];
}

__global__ __launch_bounds__(256) void k_fill(const int* __restrict__ src,
                                              const int* __restrict__ dst,
                                              const int* __restrict__ row_ptr,
                                              int* __restrict__ cnt,
                                              int* __restrict__ col, int E) {
    int e = blockIdx.x * 256 + threadIdx.x;
    if (e >= E) return;
    int d = dst[e];
    int p = atomicAdd(&cnt[d], 1);
    col[row_ptr[d] + p] = src[e];
}

// ---------------- f32 -> bf16 bulk convert (x) ----------------

__global__ __launch_bounds__(256) void k_tobf16(const float* __restrict__ x,
                                                unsigned short* __restrict__ xb, int n) {
    int i = (blockIdx.x * 256 + threadIdx.x) * 8;
    if (i >= n) return;
    float4 a = *(const float4*)&x[i];
    float4 b = *(const float4*)&x[i + 4];
    short8 v;
    v[0] = (short)f2b(a.x); v[1] = (short)f2b(a.y);
    v[2] = (short)f2b(a.z); v[3] = (short)f2b(a.w);
    v[4] = (short)f2b(b.x); v[5] = (short)f2b(b.y);
    v[6] = (short)f2b(b.z); v[7] = (short)f2b(b.w);
    *(short8*)&xb[i] = v;
}

// ---------------- mean aggregation, bf16 in/out: one wave per node ----------------

__global__ __launch_bounds__(256) void k_agg_b(const unsigned short* __restrict__ h,
                                               const int* __restrict__ row_ptr,
                                               const int* __restrict__ col,
                                               unsigned short* __restrict__ hn, int N) {
    int w = (blockIdx.x * 256 + threadIdx.x) >> 6;
    int lane = threadIdx.x & 63;
    if (w >= N) return;
    int beg = row_ptr[w], end = row_ptr[w + 1];
    float ax = 0.f, ay = 0.f;
    for (int j = beg; j < end; ++j) {
        int s = col[j];
        unsigned v = *(const unsigned*)&h[(size_t)s * D + lane * 2];
        ax += b2f_lo(v);
        ay += b2f_hi(v);
    }
    float inv = 1.0f / fmaxf((float)(end - beg), 1.0f);
    unsigned o = (unsigned)f2b(ax * inv) | ((unsigned)f2b(ay * inv) << 16);
    *(unsigned*)&hn[(size_t)w * D + lane * 2] = o;
}

// ---------------- W pre-transpose: Wt[n][k] bf16, k-stride 264, k<128 self / k>=128 neigh ----------------

#define KSTR 264  // padded k-stride (bf16 elems): 528B rows -> 16B aligned, bank-floor reads

__global__ __launch_bounds__(256) void k_prepW(const float* __restrict__ Ws,
                                               const float* __restrict__ Wn,
                                               unsigned short* __restrict__ Wt) {
    int idx = blockIdx.x * 256 + threadIdx.x;  // 32768 elems
    if (idx >= 128 * 256) return;
    int k = idx >> 7;
    int n = idx & 127;
    float v = (k < 128) ? Ws[k * 128 + n] : Wn[(k - 128) * 128 + n];
    Wt[n * KSTR + k] = f2b(v);
}

// ---------------- MFMA SAGE GEMM: out_bf16 = relu?(Ah@Ws + An@Wn + b) ----------------
// BM=64, BN=128, K=256 (k<128 from Ah, k>=128 from An). 4 waves (2 row x 2 col),
// per-wave 32x64 = 2x4 frags of 16x16, K in 8 steps of 32.

__global__ __launch_bounds__(256) void k_gemm_mfma(const unsigned short* __restrict__ Ah,
                                                   const unsigned short* __restrict__ An,
                                                   const unsigned short* __restrict__ Wt,
                                                   const float* __restrict__ bias,
                                                   unsigned short* __restrict__ out,
                                                   int N, int relu) {
    __shared__ unsigned short Wl[128 * KSTR];  // 67584 B
    int tid = threadIdx.x;
    // linear LDS stage of pre-transposed W (conflict-free b128 writes)
    for (int i = tid * 8; i < 128 * KSTR; i += 2048)
        *(short8*)&Wl[i] = *(const short8*)&Wt[i];

    int lane = tid & 63;
    int wid = tid >> 6;
    int wr = wid >> 1;        // row half
    int wc = wid & 1;         // col half
    int l15 = lane & 15;
    int kq = lane >> 4;       // 0..3
    int rowBase = blockIdx.x * 64 + wr * 32;
    int r0c = min(rowBase + l15, N - 1);
    int r1c = min(rowBase + 16 + l15, N - 1);
    int nb = wc * 64 + l15;

    f32x4 acc[2][4];
#pragma unroll
    for (int m = 0; m < 2; ++m)
#pragma unroll
        for (int r = 0; r < 4; ++r) acc[m][r] = (f32x4){0.f, 0.f, 0.f, 0.f};

    __syncthreads();

    const unsigned short* lb = &Wl[nb * KSTR + kq * 8];
#pragma unroll
    for (int s = 0; s < 8; ++s) {
        const unsigned short* A = (s < 4) ? Ah : An;
        int kk = (s & 3) * 32 + kq * 8;
        short8 a0 = *(const short8*)&A[(size_t)r0c * D + kk];
        short8 a1 = *(const short8*)&A[(size_t)r1c * D + kk];
#pragma unroll
        for (int r = 0; r < 4; ++r) {
            short8 bv = *(const short8*)&lb[s * 32 + r * (16 * KSTR)];
            acc[0][r] = __builtin_amdgcn_mfma_f32_16x16x32_bf16(a0, bv, acc[0][r], 0, 0, 0);
            acc[1][r] = __builtin_amdgcn_mfma_f32_16x16x32_bf16(a1, bv, acc[1][r], 0, 0, 0);
        }
    }

    // epilogue: C row = rowBase + m*16 + kq*4 + j, col = wc*64 + r*16 + l15
#pragma unroll
    for (int r = 0; r < 4; ++r) {
        int colIdx = wc * 64 + r * 16 + l15;
        float bb = bias[colIdx];
#pragma unroll
        for (int m = 0; m < 2; ++m) {
            int rb = rowBase + m * 16 + kq * 4;
#pragma unroll
            for (int j = 0; j < 4; ++j) {
                int row = rb + j;
                if (row < N) {
                    float v = acc[m][r][j] + bb;
                    if (relu) v = fmaxf(v, 0.f);
                    out[(size_t)row * D + colIdx] = f2b(v);
                }
            }
        }
    }
}

// ---------------- layer 2 (dout=2), bf16 h in ----------------

__global__ __launch_bounds__(256) void k_l2(const unsigned short* __restrict__ h,
                                            const float* __restrict__ Ws,
                                            const float* __restrict__ Wn,
                                            const float* __restrict__ b,
                                            float* __restrict__ out,
                                            float* __restrict__ p, int N) {
    int w = (blockIdx.x * 256 + threadIdx.x) >> 6;
    int lane = threadIdx.x & 63;
    if (w >= N) return;
    unsigned hv = *(const unsigned*)&h[(size_t)w * D + lane * 2];
    float h0 = b2f_lo(hv), h1 = b2f_hi(hv);
    float4 ws = *(const float4*)&Ws[lane * 4];
    float4 wn = *(const float4*)&Wn[lane * 4];
    float s0 = h0 * ws.x + h1 * ws.z;
    float s1 = h0 * ws.y + h1 * ws.w;
    float q0 = h0 * wn.x + h1 * wn.z;
    float q1 = h0 * wn.y + h1 * wn.w;
    for (int off = 32; off; off >>= 1) {
        s0 += __shfl_xor(s0, off);
        s1 += __shfl_xor(s1, off);
        q0 += __shfl_xor(q0, off);
        q1 += __shfl_xor(q1, off);
    }
    if (lane == 0) {
        out[w * 2 + 0] = s0 + b[0];
        out[w * 2 + 1] = s1 + b[1];
        p[w * 2 + 0] = q0;
        p[w * 2 + 1] = q1;
    }
}

__global__ __launch_bounds__(256) void k_l2agg(const float* __restrict__ p,
                                               const int* __restrict__ row_ptr,
                                               const int* __restrict__ col,
                                               float* __restrict__ out, int N) {
    int n = blockIdx.x * 256 + threadIdx.x;
    if (n >= N) return;
    int beg = row_ptr[n], end = row_ptr[n + 1];
    float a0 = 0.f, a1 = 0.f;
    for (int j = beg; j < end; ++j) {
        int s = col[j];
        float2 v = *(const float2*)&p[(size_t)s * 2];
        a0 += v.x;
        a1 += v.y;
    }
    float inv = 1.0f / fmaxf((float)(end - beg), 1.0f);
    out[n * 2 + 0] += a0 * inv;
    out[n * 2 + 1] += a1 * inv;
}

// ---------------- launch ----------------

extern "C" void kernel_launch(void* const* d_in, const int* in_sizes, int n_in,
                              void* d_out, int out_size, void* d_ws, size_t ws_size,
                              hipStream_t stream) {
    const float* x   = (const float*)d_in[0];
    const int*   src = (const int*)d_in[1];
    const int*   dst = (const int*)d_in[2];
    const float* Ws0 = (const float*)d_in[3];
    const float* Wn0 = (const float*)d_in[4];
    const float* b0  = (const float*)d_in[5];
    const float* Ws1 = (const float*)d_in[6];
    const float* Wn1 = (const float*)d_in[7];
    const float* b1  = (const float*)d_in[8];
    const float* Ws2 = (const float*)d_in[9];
    const float* Wn2 = (const float*)d_in[10];
    const float* b2  = (const float*)d_in[11];
    float* out = (float*)d_out;

    int N = in_sizes[0] / D;  // 50000
    int E = in_sizes[1];      // 600000
    size_t NB = (size_t)N * D;

    // workspace carve (~41.8 MB)
    unsigned short* B0 = (unsigned short*)d_ws;   // xb, later h2
    unsigned short* B1 = B0 + NB;                 // hn0, later hn1
    unsigned short* B2 = B1 + NB;                 // h1
    unsigned short* WT0 = B2 + NB;                // 128*KSTR bf16
    unsigned short* WT1 = WT0 + 128 * KSTR;
    float* p = (float*)(WT1 + 128 * KSTR);        // [N][2] f32
    int* row_ptr = (int*)(p + 2 * (size_t)N);     // N+1
    int* cnt     = row_ptr + (N + 2);
    int* partial = cnt + N;
    int* col     = partial + 64;                  // E

    // CSR build
    hipMemsetAsync(cnt, 0, (size_t)N * sizeof(int), stream);
    k_count<<<(E + 255) / 256, 256, 0, stream>>>(dst, cnt, E);
    int nChunks = (N + 2047) / 2048;
    k_scan_chunk<<<nChunks, 256, 0, stream>>>(cnt, row_ptr, partial, N);
    k_scan_add<<<nChunks, 256, 0, stream>>>(row_ptr, partial, N, nChunks);
    hipMemsetAsync(cnt, 0, (size_t)N * sizeof(int), stream);
    k_fill<<<(E + 255) / 256, 256, 0, stream>>>(src, dst, row_ptr, cnt, col, E);

    // weight prep + x conversion
    k_prepW<<<128, 256, 0, stream>>>(Ws0, Wn0, WT0);
    k_prepW<<<128, 256, 0, stream>>>(Ws1, Wn1, WT1);
    k_tobf16<<<(int)(NB / 8 + 255) / 256, 256, 0, stream>>>(x, B0, (int)NB);

    int aggGrid  = (N * 64 + 255) / 256;
    int gemmGrid = (N + 63) / 64;

    // layer 0: h1 = relu(x@Ws0 + mean(x)@Wn0 + b0)
    k_agg_b<<<aggGrid, 256, 0, stream>>>(B0, row_ptr, col, B1, N);
    k_gemm_mfma<<<gemmGrid, 256, 0, stream>>>(B0, B1, WT0, b0, B2, N, 1);

    // layer 1: h2 = relu(h1@Ws1 + mean(h1)@Wn1 + b1)
    k_agg_b<<<aggGrid, 256, 0, stream>>>(B2, row_ptr, col, B1, N);
    k_gemm_mfma<<<gemmGrid, 256, 0, stream>>>(B2, B1, WT1, b1, B0, N, 1);

    // layer 2: out = h2@Ws2 + mean(h2@Wn2) + b2
    k_l2<<<aggGrid, 256, 0, stream>>>(B0, Ws2, Wn2, b2, out, p, N);
    k_l2agg<<<(N + 255) / 256, 256, 0, stream>>>(p, row_ptr, col, out, N);
}

// Round 3
// 215.078 us; speedup vs baseline: 2.0539x; 1.3477x over previous
//
#include <hip/hip_runtime.h>

#define D 128

typedef __attribute__((ext_vector_type(8))) short short8;
typedef __attribute__((ext_vector_type(4))) float f32x4;

// f32 -> bf16 round-to-nearest-even
__device__ inline unsigned short f2b(float f) {
    unsigned u = __float_as_uint(f);
    u += 0x7FFFu + ((u >> 16) & 1u);
    return (unsigned short)(u >> 16);
}
__device__ inline float b2f_lo(unsigned v) { return __uint_as_float(v << 16); }
__device__ inline float b2f_hi(unsigned v) { return __uint_as_float(v & 0xFFFF0000u); }

// ---------------- CSR build ----------------

__global__ __launch_bounds__(256) void k_count(const int* __restrict__ dst,
                                               int* __restrict__ cnt, int E) {
    int e = blockIdx.x * 256 + threadIdx.x;
    if (e < E) atomicAdd(&cnt[dst[e]], 1);
}

__global__ __launch_bounds__(256) void k_scan_chunk(const int* __restrict__ cnt,
                                                    int* __restrict__ row_ptr,
                                                    int* __restrict__ partial, int N) {
    __shared__ int s[256];
    int t = threadIdx.x;
    int base = blockIdx.x * 2048 + t * 8;
    int v[8];
    int sum = 0;
#pragma unroll
    for (int i = 0; i < 8; ++i) {
        v[i] = sum;
        int idx = base + i;
        sum += (idx < N) ? cnt[idx] : 0;
    }
    s[t] = sum;
    __syncthreads();
    for (int off = 1; off < 256; off <<= 1) {
        int x = (t >= off) ? s[t - off] : 0;
        __syncthreads();
        s[t] += x;
        __syncthreads();
    }
    int exc = s[t] - sum;
#pragma unroll
    for (int i = 0; i < 8; ++i) {
        int idx = base + i;
        if (idx < N) row_ptr[idx] = exc + v[i];
    }
    if (t == 255) partial[blockIdx.x] = s[255];
}

__global__ __launch_bounds__(256) void k_scan_add(int* __restrict__ row_ptr,
                                                  const int* __restrict__ partial,
                                                  int N, int nChunks) {
    __shared__ int soff;
    int chunk = blockIdx.x;
    if (threadIdx.x == 0) {
        int o = 0;
        for (int j = 0; j < chunk; ++j) o += partial[j];
        soff = o;
    }
    __syncthreads();
    int off = soff;
    int lo = chunk * 2048;
    int hi = (chunk + 1) * 2048; if (hi > N) hi = N;
    for (int i = lo + threadIdx.x; i < hi; i += 256) row_ptr[i] += off;
    if (chunk == nChunks - 1 && threadIdx.x == 0) row_ptr[N] = off + partial[chunk];
}

__global__ __launch_bounds__(256) void k_fill(const int* __restrict__ src,
                                              const int* __restrict__ dst,
                                              const int* __restrict__ row_ptr,
                                              int* __restrict__ cnt,
                                              int* __restrict__ col, int E) {
    int e = blockIdx.x * 256 + threadIdx.x;
    if (e >= E) return;
    int d = dst[e];
    int p = atomicAdd(&cnt[d], 1);
    col[row_ptr[d] + p] = src[e];
}

// ---------------- f32 -> bf16 bulk convert (x) ----------------

__global__ __launch_bounds__(256) void k_tobf16(const float* __restrict__ x,
                                                unsigned short* __restrict__ xb, int n) {
    int i = (blockIdx.x * 256 + threadIdx.x) * 8;
    if (i >= n) return;
    float4 a = *(const float4*)&x[i];
    float4 b = *(const float4*)&x[i + 4];
    short8 v;
    v[0] = (short)f2b(a.x); v[1] = (short)f2b(a.y);
    v[2] = (short)f2b(a.z); v[3] = (short)f2b(a.w);
    v[4] = (short)f2b(b.x); v[5] = (short)f2b(b.y);
    v[6] = (short)f2b(b.z); v[7] = (short)f2b(b.w);
    *(short8*)&xb[i] = v;
}

// ---------------- mean aggregation, bf16 in/out ----------------
// one wave per node; neighbor ids prefetched lane-parallel, gathers unrolled
// 8x/4x for memory-level parallelism (latency-bound kernel, round-2 profile).

__global__ __launch_bounds__(256) void k_agg_b(const unsigned short* __restrict__ h,
                                               const int* __restrict__ row_ptr,
                                               const int* __restrict__ col,
                                               unsigned short* __restrict__ hn, int N) {
    int w = (blockIdx.x * 256 + threadIdx.x) >> 6;
    int lane = threadIdx.x & 63;
    if (w >= N) return;
    int beg = row_ptr[w], end = row_ptr[w + 1];
    int deg = end - beg;
    // parallel prefetch of up to 64 neighbor ids (one coalesced load)
    int myc = (lane < deg) ? col[beg + lane] : 0;
    int d64 = min(deg, 64);
    float ax = 0.f, ay = 0.f;
    int j = 0;
    for (; j + 8 <= d64; j += 8) {
        int s0 = __shfl(myc, j + 0), s1 = __shfl(myc, j + 1);
        int s2 = __shfl(myc, j + 2), s3 = __shfl(myc, j + 3);
        int s4 = __shfl(myc, j + 4), s5 = __shfl(myc, j + 5);
        int s6 = __shfl(myc, j + 6), s7 = __shfl(myc, j + 7);
        unsigned v0 = *(const unsigned*)&h[(size_t)s0 * D + lane * 2];
        unsigned v1 = *(const unsigned*)&h[(size_t)s1 * D + lane * 2];
        unsigned v2 = *(const unsigned*)&h[(size_t)s2 * D + lane * 2];
        unsigned v3 = *(const unsigned*)&h[(size_t)s3 * D + lane * 2];
        unsigned v4 = *(const unsigned*)&h[(size_t)s4 * D + lane * 2];
        unsigned v5 = *(const unsigned*)&h[(size_t)s5 * D + lane * 2];
        unsigned v6 = *(const unsigned*)&h[(size_t)s6 * D + lane * 2];
        unsigned v7 = *(const unsigned*)&h[(size_t)s7 * D + lane * 2];
        ax += ((b2f_lo(v0) + b2f_lo(v1)) + (b2f_lo(v2) + b2f_lo(v3)))
            + ((b2f_lo(v4) + b2f_lo(v5)) + (b2f_lo(v6) + b2f_lo(v7)));
        ay += ((b2f_hi(v0) + b2f_hi(v1)) + (b2f_hi(v2) + b2f_hi(v3)))
            + ((b2f_hi(v4) + b2f_hi(v5)) + (b2f_hi(v6) + b2f_hi(v7)));
    }
    for (; j + 4 <= d64; j += 4) {
        int s0 = __shfl(myc, j + 0), s1 = __shfl(myc, j + 1);
        int s2 = __shfl(myc, j + 2), s3 = __shfl(myc, j + 3);
        unsigned v0 = *(const unsigned*)&h[(size_t)s0 * D + lane * 2];
        unsigned v1 = *(const unsigned*)&h[(size_t)s1 * D + lane * 2];
        unsigned v2 = *(const unsigned*)&h[(size_t)s2 * D + lane * 2];
        unsigned v3 = *(const unsigned*)&h[(size_t)s3 * D + lane * 2];
        ax += (b2f_lo(v0) + b2f_lo(v1)) + (b2f_lo(v2) + b2f_lo(v3));
        ay += (b2f_hi(v0) + b2f_hi(v1)) + (b2f_hi(v2) + b2f_hi(v3));
    }
    for (; j < d64; ++j) {
        int s = __shfl(myc, j);
        unsigned v = *(const unsigned*)&h[(size_t)s * D + lane * 2];
        ax += b2f_lo(v);
        ay += b2f_hi(v);
    }
    // rare tail: deg > 64
    for (int t = beg + 64; t < end; ++t) {
        int s = col[t];
        unsigned v = *(const unsigned*)&h[(size_t)s * D + lane * 2];
        ax += b2f_lo(v);
        ay += b2f_hi(v);
    }
    float inv = 1.0f / fmaxf((float)deg, 1.0f);
    unsigned o = (unsigned)f2b(ax * inv) | ((unsigned)f2b(ay * inv) << 16);
    *(unsigned*)&hn[(size_t)w * D + lane * 2] = o;
}

// ---------------- W pre-transpose: Wt[n][k] bf16, k-stride 264 ----------------

#define KSTR 264

__global__ __launch_bounds__(256) void k_prepW(const float* __restrict__ Ws,
                                               const float* __restrict__ Wn,
                                               unsigned short* __restrict__ Wt) {
    int idx = blockIdx.x * 256 + threadIdx.x;  // 32768 elems
    if (idx >= 128 * 256) return;
    int k = idx >> 7;
    int n = idx & 127;
    float v = (k < 128) ? Ws[k * 128 + n] : Wn[(k - 128) * 128 + n];
    Wt[n * KSTR + k] = f2b(v);
}

// ---------------- MFMA SAGE GEMM: out_bf16 = relu?(Ah@Ws + An@Wn + b) ----------------

__global__ __launch_bounds__(256) void k_gemm_mfma(const unsigned short* __restrict__ Ah,
                                                   const unsigned short* __restrict__ An,
                                                   const unsigned short* __restrict__ Wt,
                                                   const float* __restrict__ bias,
                                                   unsigned short* __restrict__ out,
                                                   int N, int relu) {
    __shared__ unsigned short Wl[128 * KSTR];  // 67584 B
    int tid = threadIdx.x;
    for (int i = tid * 8; i < 128 * KSTR; i += 2048)
        *(short8*)&Wl[i] = *(const short8*)&Wt[i];

    int lane = tid & 63;
    int wid = tid >> 6;
    int wr = wid >> 1;
    int wc = wid & 1;
    int l15 = lane & 15;
    int kq = lane >> 4;
    int rowBase = blockIdx.x * 64 + wr * 32;
    int r0c = min(rowBase + l15, N - 1);
    int r1c = min(rowBase + 16 + l15, N - 1);
    int nb = wc * 64 + l15;

    f32x4 acc[2][4];
#pragma unroll
    for (int m = 0; m < 2; ++m)
#pragma unroll
        for (int r = 0; r < 4; ++r) acc[m][r] = (f32x4){0.f, 0.f, 0.f, 0.f};

    __syncthreads();

    const unsigned short* lb = &Wl[nb * KSTR + kq * 8];
#pragma unroll
    for (int s = 0; s < 8; ++s) {
        const unsigned short* A = (s < 4) ? Ah : An;
        int kk = (s & 3) * 32 + kq * 8;
        short8 a0 = *(const short8*)&A[(size_t)r0c * D + kk];
        short8 a1 = *(const short8*)&A[(size_t)r1c * D + kk];
#pragma unroll
        for (int r = 0; r < 4; ++r) {
            short8 bv = *(const short8*)&lb[s * 32 + r * (16 * KSTR)];
            acc[0][r] = __builtin_amdgcn_mfma_f32_16x16x32_bf16(a0, bv, acc[0][r], 0, 0, 0);
            acc[1][r] = __builtin_amdgcn_mfma_f32_16x16x32_bf16(a1, bv, acc[1][r], 0, 0, 0);
        }
    }

#pragma unroll
    for (int r = 0; r < 4; ++r) {
        int colIdx = wc * 64 + r * 16 + l15;
        float bb = bias[colIdx];
#pragma unroll
        for (int m = 0; m < 2; ++m) {
            int rb = rowBase + m * 16 + kq * 4;
#pragma unroll
            for (int j = 0; j < 4; ++j) {
                int row = rb + j;
                if (row < N) {
                    float v = acc[m][r][j] + bb;
                    if (relu) v = fmaxf(v, 0.f);
                    out[(size_t)row * D + colIdx] = f2b(v);
                }
            }
        }
    }
}

// ---------------- layer 2 (dout=2), bf16 h in ----------------

__global__ __launch_bounds__(256) void k_l2(const unsigned short* __restrict__ h,
                                            const float* __restrict__ Ws,
                                            const float* __restrict__ Wn,
                                            const float* __restrict__ b,
                                            float* __restrict__ out,
                                            float* __restrict__ p, int N) {
    int w = (blockIdx.x * 256 + threadIdx.x) >> 6;
    int lane = threadIdx.x & 63;
    if (w >= N) return;
    unsigned hv = *(const unsigned*)&h[(size_t)w * D + lane * 2];
    float h0 = b2f_lo(hv), h1 = b2f_hi(hv);
    float4 ws = *(const float4*)&Ws[lane * 4];
    float4 wn = *(const float4*)&Wn[lane * 4];
    float s0 = h0 * ws.x + h1 * ws.z;
    float s1 = h0 * ws.y + h1 * ws.w;
    float q0 = h0 * wn.x + h1 * wn.z;
    float q1 = h0 * wn.y + h1 * wn.w;
    for (int off = 32; off; off >>= 1) {
        s0 += __shfl_xor(s0, off);
        s1 += __shfl_xor(s1, off);
        q0 += __shfl_xor(q0, off);
        q1 += __shfl_xor(q1, off);
    }
    if (lane == 0) {
        out[w * 2 + 0] = s0 + b[0];
        out[w * 2 + 1] = s1 + b[1];
        p[w * 2 + 0] = q0;
        p[w * 2 + 1] = q1;
    }
}

__global__ __launch_bounds__(256) void k_l2agg(const float* __restrict__ p,
                                               const int* __restrict__ row_ptr,
                                               const int* __restrict__ col,
                                               float* __restrict__ out, int N) {
    int n = blockIdx.x * 256 + threadIdx.x;
    if (n >= N) return;
    int beg = row_ptr[n], end = row_ptr[n + 1];
    float a0 = 0.f, a1 = 0.f;
    for (int j = beg; j < end; ++j) {
        int s = col[j];
        float2 v = *(const float2*)&p[(size_t)s * 2];
        a0 += v.x;
        a1 += v.y;
    }
    float inv = 1.0f / fmaxf((float)(end - beg), 1.0f);
    out[n * 2 + 0] += a0 * inv;
    out[n * 2 + 1] += a1 * inv;
}

// ---------------- launch ----------------

extern "C" void kernel_launch(void* const* d_in, const int* in_sizes, int n_in,
                              void* d_out, int out_size, void* d_ws, size_t ws_size,
                              hipStream_t stream) {
    const float* x   = (const float*)d_in[0];
    const int*   src = (const int*)d_in[1];
    const int*   dst = (const int*)d_in[2];
    const float* Ws0 = (const float*)d_in[3];
    const float* Wn0 = (const float*)d_in[4];
    const float* b0  = (const float*)d_in[5];
    const float* Ws1 = (const float*)d_in[6];
    const float* Wn1 = (const float*)d_in[7];
    const float* b1  = (const float*)d_in[8];
    const float* Ws2 = (const float*)d_in[9];
    const float* Wn2 = (const float*)d_in[10];
    const float* b2  = (const float*)d_in[11];
    float* out = (float*)d_out;

    int N = in_sizes[0] / D;  // 50000
    int E = in_sizes[1];      // 600000
    size_t NB = (size_t)N * D;

    unsigned short* B0 = (unsigned short*)d_ws;   // xb, later h2
    unsigned short* B1 = B0 + NB;                 // hn0, later hn1
    unsigned short* B2 = B1 + NB;                 // h1
    unsigned short* WT0 = B2 + NB;                // 128*KSTR bf16
    unsigned short* WT1 = WT0 + 128 * KSTR;
    float* p = (float*)(WT1 + 128 * KSTR);        // [N][2] f32
    int* row_ptr = (int*)(p + 2 * (size_t)N);     // N+1
    int* cnt     = row_ptr + (N + 2);
    int* partial = cnt + N;
    int* col     = partial + 64;                  // E

    // CSR build
    hipMemsetAsync(cnt, 0, (size_t)N * sizeof(int), stream);
    k_count<<<(E + 255) / 256, 256, 0, stream>>>(dst, cnt, E);
    int nChunks = (N + 2047) / 2048;
    k_scan_chunk<<<nChunks, 256, 0, stream>>>(cnt, row_ptr, partial, N);
    k_scan_add<<<nChunks, 256, 0, stream>>>(row_ptr, partial, N, nChunks);
    hipMemsetAsync(cnt, 0, (size_t)N * sizeof(int), stream);
    k_fill<<<(E + 255) / 256, 256, 0, stream>>>(src, dst, row_ptr, cnt, col, E);

    // weight prep + x conversion
    k_prepW<<<128, 256, 0, stream>>>(Ws0, Wn0, WT0);
    k_prepW<<<128, 256, 0, stream>>>(Ws1, Wn1, WT1);
    k_tobf16<<<(int)(NB / 8 + 255) / 256, 256, 0, stream>>>(x, B0, (int)NB);

    int aggGrid  = (N * 64 + 255) / 256;
    int gemmGrid = (N + 63) / 64;

    // layer 0: h1 = relu(x@Ws0 + mean(x)@Wn0 + b0)
    k_agg_b<<<aggGrid, 256, 0, stream>>>(B0, row_ptr, col, B1, N);
    k_gemm_mfma<<<gemmGrid, 256, 0, stream>>>(B0, B1, WT0, b0, B2, N, 1);

    // layer 1: h2 = relu(h1@Ws1 + mean(h1)@Wn1 + b1)
    k_agg_b<<<aggGrid, 256, 0, stream>>>(B2, row_ptr, col, B1, N);
    k_gemm_mfma<<<gemmGrid, 256, 0, stream>>>(B2, B1, WT1, b1, B0, N, 1);

    // layer 2: out = h2@Ws2 + mean(h2@Wn2) + b2
    k_l2<<<aggGrid, 256, 0, stream>>>(B0, Ws2, Wn2, b2, out, p, N);
    k_l2agg<<<(N + 255) / 256, 256, 0, stream>>>(p, row_ptr, col, out, N);
}

// Round 4
// 202.520 us; speedup vs baseline: 2.1813x; 1.0620x over previous
//
#include <hip/hip_runtime.h>

#define D 128

typedef __attribute__((ext_vector_type(8))) short short8;
typedef __attribute__((ext_vector_type(4))) short short4v;
typedef __attribute__((ext_vector_type(4))) float f32x4;

// f32 -> bf16 round-to-nearest-even
__device__ inline unsigned short f2b(float f) {
    unsigned u = __float_as_uint(f);
    u += 0x7FFFu + ((u >> 16) & 1u);
    return (unsigned short)(u >> 16);
}
__device__ inline float b2f_lo(unsigned v) { return __uint_as_float(v << 16); }
__device__ inline float b2f_hi(unsigned v) { return __uint_as_float(v & 0xFFFF0000u); }

// ---------------- CSR build ----------------

__global__ __launch_bounds__(256) void k_count(const int* __restrict__ dst,
                                               int* __restrict__ cnt, int E) {
    int e = blockIdx.x * 256 + threadIdx.x;
    if (e < E) atomicAdd(&cnt[dst[e]], 1);
}

__global__ __launch_bounds__(256) void k_scan_chunk(const int* __restrict__ cnt,
                                                    int* __restrict__ row_ptr,
                                                    int* __restrict__ partial, int N) {
    __shared__ int s[256];
    int t = threadIdx.x;
    int base = blockIdx.x * 2048 + t * 8;
    int v[8];
    int sum = 0;
#pragma unroll
    for (int i = 0; i < 8; ++i) {
        v[i] = sum;
        int idx = base + i;
        sum += (idx < N) ? cnt[idx] : 0;
    }
    s[t] = sum;
    __syncthreads();
    for (int off = 1; off < 256; off <<= 1) {
        int x = (t >= off) ? s[t - off] : 0;
        __syncthreads();
        s[t] += x;
        __syncthreads();
    }
    int exc = s[t] - sum;
#pragma unroll
    for (int i = 0; i < 8; ++i) {
        int idx = base + i;
        if (idx < N) row_ptr[idx] = exc + v[i];
    }
    if (t == 255) partial[blockIdx.x] = s[255];
}

// adds chunk offsets; ALSO seeds cnt[] with the final row offsets (fill cursor)
__global__ __launch_bounds__(256) void k_scan_add(int* __restrict__ row_ptr,
                                                  int* __restrict__ cnt,
                                                  const int* __restrict__ partial,
                                                  int N, int nChunks) {
    __shared__ int soff;
    int chunk = blockIdx.x;
    if (threadIdx.x == 0) {
        int o = 0;
        for (int j = 0; j < chunk; ++j) o += partial[j];
        soff = o;
    }
    __syncthreads();
    int off = soff;
    int lo = chunk * 2048;
    int hi = (chunk + 1) * 2048; if (hi > N) hi = N;
    for (int i = lo + threadIdx.x; i < hi; i += 256) {
        int v = row_ptr[i] + off;
        row_ptr[i] = v;
        cnt[i] = v;  // cursor copy for k_fill
    }
    if (chunk == nChunks - 1 && threadIdx.x == 0) row_ptr[N] = off + partial[chunk];
}

// single atomic on pre-seeded cursor; no row_ptr gather, no cnt re-zero
__global__ __launch_bounds__(256) void k_fill(const int* __restrict__ src,
                                              const int* __restrict__ dst,
                                              int* __restrict__ cnt,
                                              int* __restrict__ col, int E) {
    int e = blockIdx.x * 256 + threadIdx.x;
    if (e >= E) return;
    int p = atomicAdd(&cnt[dst[e]], 1);
    col[p] = src[e];
}

// ---------------- combined prep: x->bf16 convert + W pre-transpose ----------------

#define KSTR 264

__global__ __launch_bounds__(256) void k_prep(const float* __restrict__ x,
                                              unsigned short* __restrict__ xb, int n,
                                              int nConvBlocks,
                                              const float* __restrict__ Ws0,
                                              const float* __restrict__ Wn0,
                                              const float* __restrict__ Ws1,
                                              const float* __restrict__ Wn1,
                                              unsigned short* __restrict__ WT0,
                                              unsigned short* __restrict__ WT1) {
    int bid = blockIdx.x;
    if (bid < nConvBlocks) {
        int i = (bid * 256 + threadIdx.x) * 8;
        if (i >= n) return;
        float4 a = *(const float4*)&x[i];
        float4 b = *(const float4*)&x[i + 4];
        short8 v;
        v[0] = (short)f2b(a.x); v[1] = (short)f2b(a.y);
        v[2] = (short)f2b(a.z); v[3] = (short)f2b(a.w);
        v[4] = (short)f2b(b.x); v[5] = (short)f2b(b.y);
        v[6] = (short)f2b(b.z); v[7] = (short)f2b(b.w);
        *(short8*)&xb[i] = v;
    } else {
        int idx = (bid - nConvBlocks) * 256 + threadIdx.x;  // 0..65535
        if (idx >= 2 * 128 * 256) return;
        int layer = idx >> 15;
        int r = idx & 32767;
        int k = r >> 7;
        int nn = r & 127;
        const float* Ws = layer ? Ws1 : Ws0;
        const float* Wn = layer ? Wn1 : Wn0;
        unsigned short* Wt = layer ? WT1 : WT0;
        float v = (k < 128) ? Ws[k * 128 + nn] : Wn[(k - 128) * 128 + nn];
        Wt[nn * KSTR + k] = f2b(v);
    }
}

// ---------------- mean aggregation, bf16 in/out ----------------

__global__ __launch_bounds__(256) void k_agg_b(const unsigned short* __restrict__ h,
                                               const int* __restrict__ row_ptr,
                                               const int* __restrict__ col,
                                               unsigned short* __restrict__ hn, int N) {
    int w = (blockIdx.x * 256 + threadIdx.x) >> 6;
    int lane = threadIdx.x & 63;
    if (w >= N) return;
    int beg = row_ptr[w], end = row_ptr[w + 1];
    int deg = end - beg;
    int myc = (lane < deg) ? col[beg + lane] : 0;
    int d64 = min(deg, 64);
    float ax = 0.f, ay = 0.f;
    int j = 0;
    for (; j + 8 <= d64; j += 8) {
        int s0 = __shfl(myc, j + 0), s1 = __shfl(myc, j + 1);
        int s2 = __shfl(myc, j + 2), s3 = __shfl(myc, j + 3);
        int s4 = __shfl(myc, j + 4), s5 = __shfl(myc, j + 5);
        int s6 = __shfl(myc, j + 6), s7 = __shfl(myc, j + 7);
        unsigned v0 = *(const unsigned*)&h[(size_t)s0 * D + lane * 2];
        unsigned v1 = *(const unsigned*)&h[(size_t)s1 * D + lane * 2];
        unsigned v2 = *(const unsigned*)&h[(size_t)s2 * D + lane * 2];
        unsigned v3 = *(const unsigned*)&h[(size_t)s3 * D + lane * 2];
        unsigned v4 = *(const unsigned*)&h[(size_t)s4 * D + lane * 2];
        unsigned v5 = *(const unsigned*)&h[(size_t)s5 * D + lane * 2];
        unsigned v6 = *(const unsigned*)&h[(size_t)s6 * D + lane * 2];
        unsigned v7 = *(const unsigned*)&h[(size_t)s7 * D + lane * 2];
        ax += ((b2f_lo(v0) + b2f_lo(v1)) + (b2f_lo(v2) + b2f_lo(v3)))
            + ((b2f_lo(v4) + b2f_lo(v5)) + (b2f_lo(v6) + b2f_lo(v7)));
        ay += ((b2f_hi(v0) + b2f_hi(v1)) + (b2f_hi(v2) + b2f_hi(v3)))
            + ((b2f_hi(v4) + b2f_hi(v5)) + (b2f_hi(v6) + b2f_hi(v7)));
    }
    for (; j + 4 <= d64; j += 4) {
        int s0 = __shfl(myc, j + 0), s1 = __shfl(myc, j + 1);
        int s2 = __shfl(myc, j + 2), s3 = __shfl(myc, j + 3);
        unsigned v0 = *(const unsigned*)&h[(size_t)s0 * D + lane * 2];
        unsigned v1 = *(const unsigned*)&h[(size_t)s1 * D + lane * 2];
        unsigned v2 = *(const unsigned*)&h[(size_t)s2 * D + lane * 2];
        unsigned v3 = *(const unsigned*)&h[(size_t)s3 * D + lane * 2];
        ax += (b2f_lo(v0) + b2f_lo(v1)) + (b2f_lo(v2) + b2f_lo(v3));
        ay += (b2f_hi(v0) + b2f_hi(v1)) + (b2f_hi(v2) + b2f_hi(v3));
    }
    for (; j < d64; ++j) {
        int s = __shfl(myc, j);
        unsigned v = *(const unsigned*)&h[(size_t)s * D + lane * 2];
        ax += b2f_lo(v);
        ay += b2f_hi(v);
    }
    for (int t = beg + 64; t < end; ++t) {
        int s = col[t];
        unsigned v = *(const unsigned*)&h[(size_t)s * D + lane * 2];
        ax += b2f_lo(v);
        ay += b2f_hi(v);
    }
    float inv = 1.0f / fmaxf((float)deg, 1.0f);
    unsigned o = (unsigned)f2b(ax * inv) | ((unsigned)f2b(ay * inv) << 16);
    *(unsigned*)&hn[(size_t)w * D + lane * 2] = o;
}

// ---------------- MFMA SAGE GEMM: out_bf16 = relu?(Ah@Ws + An@Wn + b) ----------------
// Operands SWAPPED in the mfma call: D = (W-frag as A) x (row-frag as B) gives the
// transposed C layout -> each lane holds row=l15, 4 CONSECUTIVE cols per frag
// -> packed 8B stores (4x fewer store instrs than 2B scatter).

__global__ __launch_bounds__(256) void k_gemm_mfma(const unsigned short* __restrict__ Ah,
                                                   const unsigned short* __restrict__ An,
                                                   const unsigned short* __restrict__ Wt,
                                                   const float* __restrict__ bias,
                                                   unsigned short* __restrict__ out,
                                                   int N, int relu) {
    __shared__ unsigned short Wl[128 * KSTR];  // 67584 B
    int tid = threadIdx.x;
    for (int i = tid * 8; i < 128 * KSTR; i += 2048)
        *(short8*)&Wl[i] = *(const short8*)&Wt[i];

    int lane = tid & 63;
    int wid = tid >> 6;
    int wr = wid >> 1;
    int wc = wid & 1;
    int l15 = lane & 15;
    int kq = lane >> 4;
    int rowBase = blockIdx.x * 64 + wr * 32;
    int r0c = min(rowBase + l15, N - 1);
    int r1c = min(rowBase + 16 + l15, N - 1);
    int nb = wc * 64 + l15;

    f32x4 acc[2][4];
#pragma unroll
    for (int m = 0; m < 2; ++m)
#pragma unroll
        for (int r = 0; r < 4; ++r) acc[m][r] = (f32x4){0.f, 0.f, 0.f, 0.f};

    __syncthreads();

    const unsigned short* lb = &Wl[nb * KSTR + kq * 8];
#pragma unroll
    for (int s = 0; s < 8; ++s) {
        const unsigned short* A = (s < 4) ? Ah : An;
        int kk = (s & 3) * 32 + kq * 8;
        short8 a0 = *(const short8*)&A[(size_t)r0c * D + kk];
        short8 a1 = *(const short8*)&A[(size_t)r1c * D + kk];
#pragma unroll
        for (int r = 0; r < 4; ++r) {
            short8 bv = *(const short8*)&lb[s * 32 + r * (16 * KSTR)];
            acc[0][r] = __builtin_amdgcn_mfma_f32_16x16x32_bf16(bv, a0, acc[0][r], 0, 0, 0);
            acc[1][r] = __builtin_amdgcn_mfma_f32_16x16x32_bf16(bv, a1, acc[1][r], 0, 0, 0);
        }
    }

    // epilogue: lane holds row = rowBase + m*16 + l15, cols = wc*64 + r*16 + kq*4 + j
    int colBase = wc * 64 + kq * 4;
#pragma unroll
    for (int m = 0; m < 2; ++m) {
        int row = rowBase + m * 16 + l15;
        if (row < N) {
#pragma unroll
            for (int r = 0; r < 4; ++r) {
                int c = colBase + r * 16;
                float4 bb = *(const float4*)&bias[c];
                float v0 = acc[m][r][0] + bb.x;
                float v1 = acc[m][r][1] + bb.y;
                float v2 = acc[m][r][2] + bb.z;
                float v3 = acc[m][r][3] + bb.w;
                if (relu) {
                    v0 = fmaxf(v0, 0.f); v1 = fmaxf(v1, 0.f);
                    v2 = fmaxf(v2, 0.f); v3 = fmaxf(v3, 0.f);
                }
                short4v o;
                o[0] = (short)f2b(v0); o[1] = (short)f2b(v1);
                o[2] = (short)f2b(v2); o[3] = (short)f2b(v3);
                *(short4v*)&out[(size_t)row * D + c] = o;
            }
        }
    }
}

// ---------------- layer 2 (dout=2), bf16 h in ----------------

__global__ __launch_bounds__(256) void k_l2(const unsigned short* __restrict__ h,
                                            const float* __restrict__ Ws,
                                            const float* __restrict__ Wn,
                                            const float* __restrict__ b,
                                            float* __restrict__ out,
                                            float* __restrict__ p, int N) {
    int w = (blockIdx.x * 256 + threadIdx.x) >> 6;
    int lane = threadIdx.x & 63;
    if (w >= N) return;
    unsigned hv = *(const unsigned*)&h[(size_t)w * D + lane * 2];
    float h0 = b2f_lo(hv), h1 = b2f_hi(hv);
    float4 ws = *(const float4*)&Ws[lane * 4];
    float4 wn = *(const float4*)&Wn[lane * 4];
    float s0 = h0 * ws.x + h1 * ws.z;
    float s1 = h0 * ws.y + h1 * ws.w;
    float q0 = h0 * wn.x + h1 * wn.z;
    float q1 = h0 * wn.y + h1 * wn.w;
    for (int off = 32; off; off >>= 1) {
        s0 += __shfl_xor(s0, off);
        s1 += __shfl_xor(s1, off);
        q0 += __shfl_xor(q0, off);
        q1 += __shfl_xor(q1, off);
    }
    if (lane == 0) {
        out[w * 2 + 0] = s0 + b[0];
        out[w * 2 + 1] = s1 + b[1];
        p[w * 2 + 0] = q0;
        p[w * 2 + 1] = q1;
    }
}

__global__ __launch_bounds__(256) void k_l2agg(const float* __restrict__ p,
                                               const int* __restrict__ row_ptr,
                                               const int* __restrict__ col,
                                               float* __restrict__ out, int N) {
    int n = blockIdx.x * 256 + threadIdx.x;
    if (n >= N) return;
    int beg = row_ptr[n], end = row_ptr[n + 1];
    float a0 = 0.f, a1 = 0.f;
    for (int j = beg; j < end; ++j) {
        int s = col[j];
        float2 v = *(const float2*)&p[(size_t)s * 2];
        a0 += v.x;
        a1 += v.y;
    }
    float inv = 1.0f / fmaxf((float)(end - beg), 1.0f);
    out[n * 2 + 0] += a0 * inv;
    out[n * 2 + 1] += a1 * inv;
}

// ---------------- launch ----------------

extern "C" void kernel_launch(void* const* d_in, const int* in_sizes, int n_in,
                              void* d_out, int out_size, void* d_ws, size_t ws_size,
                              hipStream_t stream) {
    const float* x   = (const float*)d_in[0];
    const int*   src = (const int*)d_in[1];
    const int*   dst = (const int*)d_in[2];
    const float* Ws0 = (const float*)d_in[3];
    const float* Wn0 = (const float*)d_in[4];
    const float* b0  = (const float*)d_in[5];
    const float* Ws1 = (const float*)d_in[6];
    const float* Wn1 = (const float*)d_in[7];
    const float* b1  = (const float*)d_in[8];
    const float* Ws2 = (const float*)d_in[9];
    const float* Wn2 = (const float*)d_in[10];
    const float* b2  = (const float*)d_in[11];
    float* out = (float*)d_out;

    int N = in_sizes[0] / D;  // 50000
    int E = in_sizes[1];      // 600000
    size_t NB = (size_t)N * D;

    unsigned short* B0 = (unsigned short*)d_ws;   // xb, later h2
    unsigned short* B1 = B0 + NB;                 // hn0, later hn1
    unsigned short* B2 = B1 + NB;                 // h1
    unsigned short* WT0 = B2 + NB;                // 128*KSTR bf16
    unsigned short* WT1 = WT0 + 128 * KSTR;
    float* p = (float*)(WT1 + 128 * KSTR);        // [N][2] f32
    int* row_ptr = (int*)(p + 2 * (size_t)N);     // N+1
    int* cnt     = row_ptr + (N + 2);
    int* partial = cnt + N;
    int* col     = partial + 64;                  // E

    // CSR build (cursor-seeded fill; single memset)
    hipMemsetAsync(cnt, 0, (size_t)N * sizeof(int), stream);
    k_count<<<(E + 255) / 256, 256, 0, stream>>>(dst, cnt, E);
    int nChunks = (N + 2047) / 2048;
    k_scan_chunk<<<nChunks, 256, 0, stream>>>(cnt, row_ptr, partial, N);
    k_scan_add<<<nChunks, 256, 0, stream>>>(row_ptr, cnt, partial, N, nChunks);
    k_fill<<<(E + 255) / 256, 256, 0, stream>>>(src, dst, cnt, col, E);

    // combined x->bf16 + weight prep (one dispatch)
    int nConvBlocks = (int)((NB / 8 + 255) / 256);
    k_prep<<<nConvBlocks + 256, 256, 0, stream>>>(x, B0, (int)NB, nConvBlocks,
                                                  Ws0, Wn0, Ws1, Wn1, WT0, WT1);

    int aggGrid  = (N * 64 + 255) / 256;
    int gemmGrid = (N + 63) / 64;

    // layer 0: h1 = relu(x@Ws0 + mean(x)@Wn0 + b0)
    k_agg_b<<<aggGrid, 256, 0, stream>>>(B0, row_ptr, col, B1, N);
    k_gemm_mfma<<<gemmGrid, 256, 0, stream>>>(B0, B1, WT0, b0, B2, N, 1);

    // layer 1: h2 = relu(h1@Ws1 + mean(h1)@Wn1 + b1)
    k_agg_b<<<aggGrid, 256, 0, stream>>>(B2, row_ptr, col, B1, N);
    k_gemm_mfma<<<gemmGrid, 256, 0, stream>>>(B2, B1, WT1, b1, B0, N, 1);

    // layer 2: out = h2@Ws2 + mean(h2@Wn2) + b2
    k_l2<<<aggGrid, 256, 0, stream>>>(B0, Ws2, Wn2, b2, out, p, N);
    k_l2agg<<<(N + 255) / 256, 256, 0, stream>>>(p, row_ptr, col, out, N);
}